// Round 9
// baseline (174.421 us; speedup 1.0000x reference)
//
#include <hip/hip_runtime.h>

// RDF loss: all-pairs distance histogram (10 unit bins) -> rdf -> MSE.
// Single fused kernel. Dense triangular grid of (i-tile=1024, j-chunk=32)
// blocks (2496 for N=12288, ~9.75/CU: fine granularity for packing).
// IBLK=4: each lane owns 4 i-points; one broadcast ds_read_b128 per j feeds
// 4 pairs. Pair math (unchanged, verified absmax==0 vs reference):
// Gram-form d2 (coords pre-scaled 1/dr) -> v_sqrt -> v_cvt_u32 (sat, NaN->0)
// -> min(b,10) -> u64 packed counter (10 fields x 6 bits, flushed every
// 8 j's x 4 r's = 32 adds < 63 max). Per-block partials non-atomic; LAST
// block (device-scope ticket + threadfence) reduces partials and computes
// the loss -- no second kernel, no global atomic contention.
// Reference emulation: fp32 segment_sum saturates at 2^24 -> clamp per bin.

#define BLOCK    256
#define IBLK     4
#define ITILE    (BLOCK * IBLK)   // 1024
#define JCH      32
#define DJC      (ITILE / JCH)    // 32 j-chunks per i-tile
#define NB       10
#define SLOT     16               // u32 stride between block-partial rows
#define FP32_SAT 16777216u        // 2^24

__device__ __forceinline__ int pre_rows(int k, int njc) {
    // blocks before i-tile k: sum_{m<k} (njc - DJC*m)
    return k * njc - (DJC / 2) * k * (k - 1);
}

template <bool STRADDLE>
__device__ __forceinline__ void jloop(const float4* __restrict__ sj,
                                      const float* sqi, const float* m2x,
                                      const float* m2y, const float* m2z,
                                      const int* iidx, int jbase,
                                      unsigned int* c)
{
    #pragma unroll
    for (int jc0 = 0; jc0 < JCH; jc0 += 8) {
        unsigned long long cnt = 0ull;
        #pragma unroll
        for (int jj = 0; jj < 8; ++jj) {
            const int j = jc0 + jj;
            float4 p = sj[j];
            #pragma unroll
            for (int r = 0; r < IBLK; ++r) {
                float d2 = sqi[r] + p.w;
                d2 = fmaf(m2x[r], p.x, d2);
                d2 = fmaf(m2y[r], p.y, d2);
                d2 = fmaf(m2z[r], p.z, d2);
                if (STRADDLE) d2 = (jbase + j > iidx[r]) ? d2 : 3.0e30f;
                float d = __builtin_amdgcn_sqrtf(d2);
                unsigned int b = (unsigned int)d;   // v_cvt_u32_f32: sat, NaN->0
                b = min(b, 10u);                    // 10 = trash field (bits 60+)
                cnt += 1ull << (b * 6u);
            }
        }
        #pragma unroll
        for (int k = 0; k < NB; ++k)
            c[k] += (unsigned int)(cnt >> (6 * k)) & 63u;
    }
}

__global__ __launch_bounds__(BLOCK, 8) void rdf_fused_kernel(
    const float* __restrict__ pc, const float* __restrict__ target,
    const int* __restrict__ rmaxp, const float* __restrict__ drp,
    unsigned int* __restrict__ part, unsigned int* __restrict__ done,
    float* __restrict__ out, int n, int mt, int nI, int njc, int nblocks)
{
    __shared__ float4 sj[JCH];
    __shared__ unsigned int sacc[NB];
    __shared__ unsigned int amlast;

    const int tid = threadIdx.x;
    const int bid = (int)blockIdx.x;

    // decode dense triangular work index -> (i-tile k, j-chunk jc)
    const float a  = (float)(DJC / 2);                 // 16
    const float bq = (float)njc + a;
    float disc = fmaxf(bq * bq - 4.0f * a * (float)bid, 0.0f);
    int k = (int)((bq - sqrtf(disc)) / (2.0f * a));
    k = max(0, min(k, nI - 1));
    while (k > 0 && pre_rows(k, njc) > bid) --k;
    while (k + 1 < nI && pre_rows(k + 1, njc) <= bid) ++k;
    const int jc    = (bid - pre_rows(k, njc)) + DJC * k;
    const int ibase = k * ITILE;
    const int jbase = jc * JCH;

    const float inv_dr = 1.0f / (*drp);

    // issue all raw global loads before first use (single latency drain)
    float jx = -3.0e4f, jy = -3.0e4f, jz = -3.0e4f;    // j-pad sentinel
    if (tid < JCH) {
        const int j = jbase + tid;
        if (j < n) { jx = pc[3*j]; jy = pc[3*j+1]; jz = pc[3*j+2]; }
    }
    float rx[IBLK], ry[IBLK], rz[IBLK];
    int iidx[IBLK];
    #pragma unroll
    for (int r = 0; r < IBLK; ++r) {
        const int i = ibase + tid + BLOCK * r;
        iidx[r] = i;
        rx[r] = 3.0e4f; ry[r] = 3.0e4f; rz[r] = 3.0e4f; // i-pad: opposite sign
        if (i < n) { rx[r] = pc[3*i]; ry[r] = pc[3*i+1]; rz[r] = pc[3*i+2]; }
    }

    if (tid < NB) sacc[tid] = 0u;
    if (tid < JCH) {
        const float x = jx * inv_dr, y = jy * inv_dr, z = jz * inv_dr;
        sj[tid] = make_float4(x, y, z, x*x + y*y + z*z);
    }
    float sqi[IBLK], m2x[IBLK], m2y[IBLK], m2z[IBLK];
    #pragma unroll
    for (int r = 0; r < IBLK; ++r) {
        const float x = rx[r] * inv_dr, y = ry[r] * inv_dr, z = rz[r] * inv_dr;
        sqi[r] = x*x + y*y + z*z;
        m2x[r] = -2.f * x; m2y[r] = -2.f * y; m2z[r] = -2.f * z;
    }

    __syncthreads();

    unsigned int c[NB];
    #pragma unroll
    for (int q = 0; q < NB; ++q) c[q] = 0u;

    if (jbase < ibase + ITILE)                  // chunk straddles diagonal band
        jloop<true >(sj, sqi, m2x, m2y, m2z, iidx, jbase, c);
    else
        jloop<false>(sj, sqi, m2x, m2y, m2z, iidx, jbase, c);

    // wave butterfly -> LDS combine -> one non-atomic partial row per block
    #pragma unroll
    for (int q = 0; q < NB; ++q) {
        unsigned int s = c[q];
        #pragma unroll
        for (int m = 32; m >= 1; m >>= 1) s += (unsigned int)__shfl_xor((int)s, m, 64);
        c[q] = s;
    }
    if ((tid & 63) == 0) {
        #pragma unroll
        for (int q = 0; q < NB; ++q) atomicAdd(&sacc[q], c[q]);
    }
    __syncthreads();
    if (tid < NB) part[bid * SLOT + tid] = sacc[tid];

    // ---- last-block reduction + loss (device-scope ticket) ----
    __threadfence();
    if (tid == 0)
        amlast = (atomicAdd(done, 1u) == (unsigned int)(nblocks - 1)) ? 1u : 0u;
    __syncthreads();
    if (!amlast) return;
    __threadfence();                           // acquire: see all part writes

    unsigned int acc2[NB];
    #pragma unroll
    for (int q = 0; q < NB; ++q) acc2[q] = 0u;
    for (int s = tid; s < nblocks; s += BLOCK) {
        #pragma unroll
        for (int q = 0; q < NB; ++q) acc2[q] += part[s * SLOT + q];
    }
    if (tid < NB) sacc[tid] = 0u;
    __syncthreads();
    #pragma unroll
    for (int q = 0; q < NB; ++q) {
        unsigned int s = acc2[q];
        #pragma unroll
        for (int m = 32; m >= 1; m >>= 1) s += (unsigned int)__shfl_xor((int)s, m, 64);
        if ((tid & 63) == 0) atomicAdd(&sacc[q], s);
    }
    __syncthreads();

    if (tid == 0) {
        const float PI = 3.14159265358979323846f;
        const float rmax = (float)(*rmaxp);
        const float dr   = *drp;
        int nbins = (int)roundf(rmax / dr);
        if (nbins > NB) nbins = NB;
        const float density = (float)n / (4.0f / 3.0f * PI * rmax * rmax * rmax);
        const int m = (mt < nbins) ? mt : nbins;
        float acc = 0.0f;
        for (int b = 0; b < m; ++b) {
            unsigned int hb = 2u * sacc[b] + ((b == 0) ? (unsigned int)n : 0u);
            if (hb > FP32_SAT) hb = FP32_SAT;   // fp32 segment_sum saturation
            float r_mid = ((float)b + 0.5f) * dr;
            float ideal = 4.0f * PI * r_mid * r_mid * dr * density * (float)n;
            float rdf  = (ideal != 0.0f) ? ((float)hb / ideal) : 0.0f;
            float diff = rdf - target[b];
            acc = fmaf(diff, diff, acc);
        }
        out[0] = acc / (float)m;
    }
}

extern "C" void kernel_launch(void* const* d_in, const int* in_sizes, int n_in,
                              void* d_out, int out_size, void* d_ws, size_t ws_size,
                              hipStream_t stream)
{
    const float* pc     = (const float*)d_in[0];
    const float* target = (const float*)d_in[1];
    const int*   rmaxp  = (const int*)d_in[2];
    const float* drp    = (const float*)d_in[3];
    const int n  = in_sizes[0] / 3;
    const int mt = in_sizes[1];

    unsigned int* done = (unsigned int*)d_ws;                 // 1 counter (own line)
    unsigned int* part = (unsigned int*)((char*)d_ws + 256);  // partial rows

    const int nI  = (n + ITILE - 1) / ITILE;
    const int njc = (n + JCH - 1) / JCH;
    const int nblocks = nI * njc - (DJC / 2) * nI * (nI - 1); // dense triangle

    hipMemsetAsync(done, 0, 256, stream);
    rdf_fused_kernel<<<nblocks, BLOCK, 0, stream>>>(
        pc, target, rmaxp, drp, part, done, (float*)d_out, n, mt, nI, njc, nblocks);
}

// Round 10
// 43.795 us; speedup vs baseline: 3.9827x; 3.9827x over previous
//
#include <hip/hip_runtime.h>

// RDF loss: all-pairs distance histogram (10 unit bins) -> rdf -> MSE.
// Two kernels (round-9 lesson: fused last-block ticket + __threadfence
// serialized the whole device -> 17% VALUBusy; non-atomic partials + tiny
// reduce kernel is the fast structure). Dense triangular grid of
// (i-tile=1024, j-chunk=32) blocks: 2496 blocks for N=12288 = 9.75/CU,
// filling all 8 wave-slots/SIMD (round-8 had only 4.9/CU -> idle slots).
// IBLK=4: each lane owns 4 i-points; one broadcast ds_read_b128 per j feeds
// 4 pairs. Pair math (verified absmax==0 vs reference): Gram-form d2
// (coords pre-scaled 1/dr) -> v_sqrt -> v_cvt_u32 (sat, NaN->0) ->
// min(b,10) -> u64 packed counter (10 fields x 6 bits, flushed every
// 8 j's x 4 r's = 32 adds < 63 max).
// Reference emulation: fp32 segment_sum saturates at 2^24 -> clamp per bin.

#define BLOCK    256
#define IBLK     4
#define ITILE    (BLOCK * IBLK)   // 1024
#define JCH      32
#define DJC      (ITILE / JCH)    // 32 j-chunks per i-tile
#define NB       10
#define SLOT     16               // u32 stride between block-partial rows
#define FP32_SAT 16777216u        // 2^24

__device__ __forceinline__ int pre_rows(int k, int njc) {
    // blocks before i-tile k: sum_{m<k} (njc - DJC*m)
    return k * njc - (DJC / 2) * k * (k - 1);
}

template <bool STRADDLE>
__device__ __forceinline__ void jloop(const float4* __restrict__ sj,
                                      const float* sqi, const float* m2x,
                                      const float* m2y, const float* m2z,
                                      const int* iidx, int jbase,
                                      unsigned int* c)
{
    #pragma unroll
    for (int jc0 = 0; jc0 < JCH; jc0 += 8) {
        unsigned long long cnt = 0ull;
        #pragma unroll
        for (int jj = 0; jj < 8; ++jj) {
            const int j = jc0 + jj;
            float4 p = sj[j];
            #pragma unroll
            for (int r = 0; r < IBLK; ++r) {
                float d2 = sqi[r] + p.w;
                d2 = fmaf(m2x[r], p.x, d2);
                d2 = fmaf(m2y[r], p.y, d2);
                d2 = fmaf(m2z[r], p.z, d2);
                if (STRADDLE) d2 = (jbase + j > iidx[r]) ? d2 : 3.0e30f;
                float d = __builtin_amdgcn_sqrtf(d2);
                unsigned int b = (unsigned int)d;   // v_cvt_u32_f32: sat, NaN->0
                b = min(b, 10u);                    // 10 = trash field (bits 60+)
                cnt += 1ull << (b * 6u);
            }
        }
        #pragma unroll
        for (int k = 0; k < NB; ++k)
            c[k] += (unsigned int)(cnt >> (6 * k)) & 63u;
    }
}

__global__ __launch_bounds__(BLOCK, 8) void rdf_hist_kernel(
    const float* __restrict__ pc, const int* __restrict__ rmaxp,
    const float* __restrict__ drp, unsigned int* __restrict__ part,
    int n, int nI, int njc)
{
    __shared__ float4 sj[JCH];
    __shared__ unsigned int sacc[NB];

    const int tid = threadIdx.x;
    const int bid = (int)blockIdx.x;

    // decode dense triangular work index -> (i-tile k, j-chunk jc)
    const float a  = (float)(DJC / 2);                 // 16
    const float bq = (float)njc + a;
    float disc = fmaxf(bq * bq - 4.0f * a * (float)bid, 0.0f);
    int k = (int)((bq - sqrtf(disc)) / (2.0f * a));
    k = max(0, min(k, nI - 1));
    while (k > 0 && pre_rows(k, njc) > bid) --k;
    while (k + 1 < nI && pre_rows(k + 1, njc) <= bid) ++k;
    const int jc    = (bid - pre_rows(k, njc)) + DJC * k;
    const int ibase = k * ITILE;
    const int jbase = jc * JCH;

    const float inv_dr = 1.0f / (*drp);

    // issue all raw global loads before first use (single latency drain)
    float jx = -3.0e4f, jy = -3.0e4f, jz = -3.0e4f;    // j-pad sentinel
    if (tid < JCH) {
        const int j = jbase + tid;
        if (j < n) { jx = pc[3*j]; jy = pc[3*j+1]; jz = pc[3*j+2]; }
    }
    float rx[IBLK], ry[IBLK], rz[IBLK];
    int iidx[IBLK];
    #pragma unroll
    for (int r = 0; r < IBLK; ++r) {
        const int i = ibase + tid + BLOCK * r;
        iidx[r] = i;
        rx[r] = 3.0e4f; ry[r] = 3.0e4f; rz[r] = 3.0e4f; // i-pad: opposite sign
        if (i < n) { rx[r] = pc[3*i]; ry[r] = pc[3*i+1]; rz[r] = pc[3*i+2]; }
    }

    if (tid < NB) sacc[tid] = 0u;
    if (tid < JCH) {
        const float x = jx * inv_dr, y = jy * inv_dr, z = jz * inv_dr;
        sj[tid] = make_float4(x, y, z, x*x + y*y + z*z);
    }
    float sqi[IBLK], m2x[IBLK], m2y[IBLK], m2z[IBLK];
    #pragma unroll
    for (int r = 0; r < IBLK; ++r) {
        const float x = rx[r] * inv_dr, y = ry[r] * inv_dr, z = rz[r] * inv_dr;
        sqi[r] = x*x + y*y + z*z;
        m2x[r] = -2.f * x; m2y[r] = -2.f * y; m2z[r] = -2.f * z;
    }

    __syncthreads();

    unsigned int c[NB];
    #pragma unroll
    for (int q = 0; q < NB; ++q) c[q] = 0u;

    if (jbase < ibase + ITILE)                  // chunk straddles diagonal band
        jloop<true >(sj, sqi, m2x, m2y, m2z, iidx, jbase, c);
    else
        jloop<false>(sj, sqi, m2x, m2y, m2z, iidx, jbase, c);

    // wave butterfly -> LDS combine -> one non-atomic partial row per block
    #pragma unroll
    for (int q = 0; q < NB; ++q) {
        unsigned int s = c[q];
        #pragma unroll
        for (int m = 32; m >= 1; m >>= 1) s += (unsigned int)__shfl_xor((int)s, m, 64);
        c[q] = s;
    }
    if ((tid & 63) == 0) {
        #pragma unroll
        for (int q = 0; q < NB; ++q) atomicAdd(&sacc[q], c[q]);
    }
    __syncthreads();
    if (tid < NB) part[bid * SLOT + tid] = sacc[tid];
}

__global__ __launch_bounds__(BLOCK) void rdf_reduce_loss_kernel(
    const unsigned int* __restrict__ part, const float* __restrict__ target,
    const int* __restrict__ rmaxp, const float* __restrict__ drp,
    float* __restrict__ out, int n, int mt, int nblocks)
{
    __shared__ unsigned int sacc[NB];
    const int tid = threadIdx.x;
    if (tid < NB) sacc[tid] = 0u;
    __syncthreads();

    unsigned int a[NB];
    #pragma unroll
    for (int q = 0; q < NB; ++q) a[q] = 0u;
    for (int s = tid; s < nblocks; s += BLOCK) {
        #pragma unroll
        for (int q = 0; q < NB; ++q) a[q] += part[s * SLOT + q];
    }
    #pragma unroll
    for (int q = 0; q < NB; ++q) {
        unsigned int s = a[q];
        #pragma unroll
        for (int m = 32; m >= 1; m >>= 1) s += (unsigned int)__shfl_xor((int)s, m, 64);
        if ((tid & 63) == 0) atomicAdd(&sacc[q], s);
    }
    __syncthreads();

    if (tid == 0) {
        const float PI = 3.14159265358979323846f;
        const float rmax = (float)(*rmaxp);
        const float dr   = *drp;
        int nbins = (int)roundf(rmax / dr);
        if (nbins > NB) nbins = NB;
        const float density = (float)n / (4.0f / 3.0f * PI * rmax * rmax * rmax);
        const int m = (mt < nbins) ? mt : nbins;
        float acc = 0.0f;
        for (int b = 0; b < m; ++b) {
            unsigned int hb = 2u * sacc[b] + ((b == 0) ? (unsigned int)n : 0u);
            if (hb > FP32_SAT) hb = FP32_SAT;   // fp32 segment_sum saturation
            float r_mid = ((float)b + 0.5f) * dr;
            float ideal = 4.0f * PI * r_mid * r_mid * dr * density * (float)n;
            float rdf  = (ideal != 0.0f) ? ((float)hb / ideal) : 0.0f;
            float diff = rdf - target[b];
            acc = fmaf(diff, diff, acc);
        }
        out[0] = acc / (float)m;
    }
}

extern "C" void kernel_launch(void* const* d_in, const int* in_sizes, int n_in,
                              void* d_out, int out_size, void* d_ws, size_t ws_size,
                              hipStream_t stream)
{
    const float* pc     = (const float*)d_in[0];
    const float* target = (const float*)d_in[1];
    const int*   rmaxp  = (const int*)d_in[2];
    const float* drp    = (const float*)d_in[3];
    const int n  = in_sizes[0] / 3;
    const int mt = in_sizes[1];

    unsigned int* part = (unsigned int*)d_ws;
    const int nI  = (n + ITILE - 1) / ITILE;
    const int njc = (n + JCH - 1) / JCH;
    const int nblocks = nI * njc - (DJC / 2) * nI * (nI - 1); // dense triangle

    rdf_hist_kernel<<<nblocks, BLOCK, 0, stream>>>(pc, rmaxp, drp, part, n, nI, njc);
    rdf_reduce_loss_kernel<<<1, BLOCK, 0, stream>>>(part, target, rmaxp, drp,
                                                    (float*)d_out, n, mt, nblocks);
}

// Round 11
// 39.714 us; speedup vs baseline: 4.3919x; 1.1027x over previous
//
#include <hip/hip_runtime.h>

// RDF loss: all-pairs distance histogram (10 unit bins) -> rdf -> MSE.
// Two kernels (r9 lesson: device-fence ticket serializes). Dense triangular
// grid of (i-tile=1024, j-chunk=64) blocks: 1248 uniform blocks for N=12288.
// IBLK=4 i-points/lane as TWO f32x2 chains: v_pk_fma_f32 (2 fp32 FMA/instr,
// full rate -- scalar fma is half the chip's fp32 rate) computes two pair
// d2's per instruction. No launch_bounds min-wave clamp (r10 VGPR=32 choked
// ILP; let regalloc keep 32 independent pair-chains in flight).
// Pair math (value-identical to verified rounds): Gram-form d2 (coords
// pre-scaled 1/dr) -> v_sqrt -> v_cvt_u32 (sat, NaN->0) -> min(b,10) ->
// u64 packed counter (10 fields x 6 bits, flushed every 8 j x 4 r = 32 adds).
// Reference emulation: fp32 segment_sum saturates at 2^24 -> clamp per bin.

#define BLOCK    256
#define IBLK     4
#define ITILE    (BLOCK * IBLK)   // 1024
#define JCH      64
#define DJC      (ITILE / JCH)    // 16 j-chunks per i-tile
#define NB       10
#define SLOT     16               // u32 stride between block-partial rows
#define FP32_SAT 16777216u        // 2^24

typedef float f32x2 __attribute__((ext_vector_type(2)));

__device__ __forceinline__ int pre_rows(int k, int njc) {
    // blocks before i-tile k: sum_{m<k} (njc - DJC*m)
    return k * njc - (DJC / 2) * k * (k - 1);
}

template <bool STRADDLE>
__device__ __forceinline__ void jloop(const float4* __restrict__ sj,
                                      const f32x2* sqiv, const f32x2* m2xv,
                                      const f32x2* m2yv, const f32x2* m2zv,
                                      const int* iidx, int jbase,
                                      unsigned int* c)
{
    #pragma unroll
    for (int jc0 = 0; jc0 < JCH; jc0 += 8) {
        unsigned long long cnt = 0ull;
        #pragma unroll
        for (int jj = 0; jj < 8; ++jj) {
            const int j = jc0 + jj;
            float4 p = sj[j];
            const f32x2 pw = {p.w, p.w}, px = {p.x, p.x};
            const f32x2 py = {p.y, p.y}, pz = {p.z, p.z};
            #pragma unroll
            for (int rp = 0; rp < IBLK / 2; ++rp) {
                f32x2 d2 = sqiv[rp] + pw;
                d2 = __builtin_elementwise_fma(m2xv[rp], px, d2);  // v_pk_fma_f32
                d2 = __builtin_elementwise_fma(m2yv[rp], py, d2);
                d2 = __builtin_elementwise_fma(m2zv[rp], pz, d2);
                float d2a = d2.x, d2b = d2.y;
                if (STRADDLE) {
                    d2a = (jbase + j > iidx[2 * rp])     ? d2a : 3.0e30f;
                    d2b = (jbase + j > iidx[2 * rp + 1]) ? d2b : 3.0e30f;
                }
                float da = __builtin_amdgcn_sqrtf(d2a);
                float db = __builtin_amdgcn_sqrtf(d2b);
                unsigned int ba = min((unsigned int)da, 10u);  // cvt sat, NaN->0
                unsigned int bb = min((unsigned int)db, 10u);  // 10 = trash field
                cnt += 1ull << (ba * 6u);
                cnt += 1ull << (bb * 6u);
            }
        }
        #pragma unroll
        for (int k = 0; k < NB; ++k)
            c[k] += (unsigned int)(cnt >> (6 * k)) & 63u;
    }
}

__global__ __launch_bounds__(BLOCK) void rdf_hist_kernel(
    const float* __restrict__ pc, const int* __restrict__ rmaxp,
    const float* __restrict__ drp, unsigned int* __restrict__ part,
    int n, int nI, int njc)
{
    __shared__ float4 sj[JCH];
    __shared__ unsigned int sacc[NB];

    const int tid = threadIdx.x;
    const int bid = (int)blockIdx.x;

    // decode dense triangular work index -> (i-tile k, j-chunk jc)
    const float a  = (float)(DJC / 2);                 // 8
    const float bq = (float)njc + a;
    float disc = fmaxf(bq * bq - 4.0f * a * (float)bid, 0.0f);
    int k = (int)((bq - sqrtf(disc)) / (2.0f * a));
    k = max(0, min(k, nI - 1));
    while (k > 0 && pre_rows(k, njc) > bid) --k;
    while (k + 1 < nI && pre_rows(k + 1, njc) <= bid) ++k;
    const int jc    = (bid - pre_rows(k, njc)) + DJC * k;
    const int ibase = k * ITILE;
    const int jbase = jc * JCH;

    const float inv_dr = 1.0f / (*drp);

    // issue all raw global loads before first use (single latency drain)
    float jx = -3.0e4f, jy = -3.0e4f, jz = -3.0e4f;    // j-pad sentinel
    if (tid < JCH) {
        const int j = jbase + tid;
        if (j < n) { jx = pc[3*j]; jy = pc[3*j+1]; jz = pc[3*j+2]; }
    }
    float rx[IBLK], ry[IBLK], rz[IBLK];
    int iidx[IBLK];
    #pragma unroll
    for (int r = 0; r < IBLK; ++r) {
        const int i = ibase + tid + BLOCK * r;
        iidx[r] = i;
        rx[r] = 3.0e4f; ry[r] = 3.0e4f; rz[r] = 3.0e4f; // i-pad: opposite sign
        if (i < n) { rx[r] = pc[3*i]; ry[r] = pc[3*i+1]; rz[r] = pc[3*i+2]; }
    }

    if (tid < NB) sacc[tid] = 0u;
    if (tid < JCH) {
        const float x = jx * inv_dr, y = jy * inv_dr, z = jz * inv_dr;
        sj[tid] = make_float4(x, y, z, x*x + y*y + z*z);
    }
    f32x2 sqiv[IBLK/2], m2xv[IBLK/2], m2yv[IBLK/2], m2zv[IBLK/2];
    #pragma unroll
    for (int r = 0; r < IBLK; ++r) {
        const float x = rx[r] * inv_dr, y = ry[r] * inv_dr, z = rz[r] * inv_dr;
        const float sq = x*x + y*y + z*z;
        sqiv[r/2][r&1] = sq;
        m2xv[r/2][r&1] = -2.f * x;
        m2yv[r/2][r&1] = -2.f * y;
        m2zv[r/2][r&1] = -2.f * z;
    }

    __syncthreads();

    unsigned int c[NB];
    #pragma unroll
    for (int q = 0; q < NB; ++q) c[q] = 0u;

    if (jbase < ibase + ITILE)                  // chunk straddles diagonal band
        jloop<true >(sj, sqiv, m2xv, m2yv, m2zv, iidx, jbase, c);
    else
        jloop<false>(sj, sqiv, m2xv, m2yv, m2zv, iidx, jbase, c);

    // wave butterfly -> LDS combine -> one non-atomic partial row per block
    #pragma unroll
    for (int q = 0; q < NB; ++q) {
        unsigned int s = c[q];
        #pragma unroll
        for (int m = 32; m >= 1; m >>= 1) s += (unsigned int)__shfl_xor((int)s, m, 64);
        c[q] = s;
    }
    if ((tid & 63) == 0) {
        #pragma unroll
        for (int q = 0; q < NB; ++q) atomicAdd(&sacc[q], c[q]);
    }
    __syncthreads();
    if (tid < NB) part[bid * SLOT + tid] = sacc[tid];
}

__global__ __launch_bounds__(BLOCK) void rdf_reduce_loss_kernel(
    const unsigned int* __restrict__ part, const float* __restrict__ target,
    const int* __restrict__ rmaxp, const float* __restrict__ drp,
    float* __restrict__ out, int n, int mt, int nblocks)
{
    __shared__ unsigned int sacc[NB];
    const int tid = threadIdx.x;
    if (tid < NB) sacc[tid] = 0u;
    __syncthreads();

    unsigned int a[NB];
    #pragma unroll
    for (int q = 0; q < NB; ++q) a[q] = 0u;
    for (int s = tid; s < nblocks; s += BLOCK) {
        #pragma unroll
        for (int q = 0; q < NB; ++q) a[q] += part[s * SLOT + q];
    }
    #pragma unroll
    for (int q = 0; q < NB; ++q) {
        unsigned int s = a[q];
        #pragma unroll
        for (int m = 32; m >= 1; m >>= 1) s += (unsigned int)__shfl_xor((int)s, m, 64);
        if ((tid & 63) == 0) atomicAdd(&sacc[q], s);
    }
    __syncthreads();

    if (tid == 0) {
        const float PI = 3.14159265358979323846f;
        const float rmax = (float)(*rmaxp);
        const float dr   = *drp;
        int nbins = (int)roundf(rmax / dr);
        if (nbins > NB) nbins = NB;
        const float density = (float)n / (4.0f / 3.0f * PI * rmax * rmax * rmax);
        const int m = (mt < nbins) ? mt : nbins;
        float acc = 0.0f;
        for (int b = 0; b < m; ++b) {
            unsigned int hb = 2u * sacc[b] + ((b == 0) ? (unsigned int)n : 0u);
            if (hb > FP32_SAT) hb = FP32_SAT;   // fp32 segment_sum saturation
            float r_mid = ((float)b + 0.5f) * dr;
            float ideal = 4.0f * PI * r_mid * r_mid * dr * density * (float)n;
            float rdf  = (ideal != 0.0f) ? ((float)hb / ideal) : 0.0f;
            float diff = rdf - target[b];
            acc = fmaf(diff, diff, acc);
        }
        out[0] = acc / (float)m;
    }
}

extern "C" void kernel_launch(void* const* d_in, const int* in_sizes, int n_in,
                              void* d_out, int out_size, void* d_ws, size_t ws_size,
                              hipStream_t stream)
{
    const float* pc     = (const float*)d_in[0];
    const float* target = (const float*)d_in[1];
    const int*   rmaxp  = (const int*)d_in[2];
    const float* drp    = (const float*)d_in[3];
    const int n  = in_sizes[0] / 3;
    const int mt = in_sizes[1];

    unsigned int* part = (unsigned int*)d_ws;
    const int nI  = (n + ITILE - 1) / ITILE;
    const int njc = (n + JCH - 1) / JCH;
    const int nblocks = nI * njc - (DJC / 2) * nI * (nI - 1); // dense triangle

    rdf_hist_kernel<<<nblocks, BLOCK, 0, stream>>>(pc, rmaxp, drp, part, n, nI, njc);
    rdf_reduce_loss_kernel<<<1, BLOCK, 0, stream>>>(part, target, rmaxp, drp,
                                                    (float*)d_out, n, mt, nblocks);
}